// Round 2
// baseline (482.574 us; speedup 1.0000x reference)
//
#include <hip/hip_runtime.h>

// VectorQuantizer: z (8,64,8192) f32, codebook (1024,64) f32
// Outputs (concatenated f32): z_q_st [4194304], vq_loss [1], codes [65536]
//
// Key constraint: codes must match the numpy fp32 reference argmin BIT-EXACTLY.
// The reference's distances round at magnitude ~64 (ulp 7.6e-6) while top-2
// gaps can be far smaller, so we replicate numpy's exact fp32 op order:
//   sq    = fl(x*x) elementwise (materialized, rounded)          [__fmul_rn]
//   sum64 = numpy pairwise_sum n=64: 8 serial accumulators r[k]=sum sq[k+8j],
//           combined ((r0+r1)+(r2+r3))+((r4+r5)+(r6+r7))         [__fadd_rn]
//   dot   = BLAS sgemm: single serial FMA chain over k ascending [fmaf]
//   d     = fl(fl(zsq - fl(2*dot)) + wsq)                        [unfused]
//   argmin: first occurrence of minimum.

#define T_DIM 8192
#define D_DIM 64
#define C_DIM 1024
#define B_DIM 8
#define NROWS (B_DIM * T_DIM)           // 65536 vectors
#define NELEM (B_DIM * D_DIM * T_DIM)   // 4194304 elements
#define SEGS 4
#define CODES_PER_SEG (C_DIM / SEGS)    // 256

// numpy pairwise_sum for exactly 64 pre-rounded squares, unfused adds.
__device__ __forceinline__ float np_pairwise_sum64_sq(const float* x) {
    float r[8];
#pragma unroll
    for (int k = 0; k < 8; ++k) r[k] = __fmul_rn(x[k], x[k]);
#pragma unroll
    for (int i = 8; i < 64; i += 8) {
#pragma unroll
        for (int k = 0; k < 8; ++k)
            r[k] = __fadd_rn(r[k], __fmul_rn(x[i + k], x[i + k]));
    }
    return __fadd_rn(
        __fadd_rn(__fadd_rn(r[0], r[1]), __fadd_rn(r[2], r[3])),
        __fadd_rn(__fadd_rn(r[4], r[5]), __fadd_rn(r[6], r[7])));
}

__global__ void vq_wsq_kernel(const float* __restrict__ cb,
                              float* __restrict__ wsq) {
    int c = blockIdx.x * blockDim.x + threadIdx.x;
    if (c >= C_DIM) return;
    float w[64];
    const float4* wp = (const float4*)(cb + (c << 6));
#pragma unroll
    for (int j = 0; j < 16; ++j) {
        float4 v = wp[j];
        w[4 * j + 0] = v.x; w[4 * j + 1] = v.y;
        w[4 * j + 2] = v.z; w[4 * j + 3] = v.w;
    }
    wsq[c] = np_pairwise_sum64_sq(w);
}

// One thread per row; blockIdx.y selects a 256-code segment (wave-uniform ->
// codebook reads become scalar loads). Serial FMA chain per code replicates
// BLAS sgemm accumulation order; 4 codes in flight for ILP.
__global__ __launch_bounds__(256, 4)
void vq_dist_kernel(const float* __restrict__ z,
                    const float* __restrict__ cb,
                    const float* __restrict__ wsq,
                    float2* __restrict__ pairs) {
    const int row = blockIdx.x * 256 + threadIdx.x;   // 0..65535
    const int seg = blockIdx.y;                       // 0..3 (uniform)
    const int b = row >> 13;                          // row / 8192
    const int t = row & (T_DIM - 1);

    // z[b, d, t]: stride T_DIM along d; lanes t-consecutive -> coalesced
    const float* zp = z + (size_t)b * (D_DIM * T_DIM) + t;
    float zr[D_DIM];
#pragma unroll
    for (int d = 0; d < D_DIM; ++d) zr[d] = zp[(size_t)d * T_DIM];

    // ||z||^2 with numpy's exact pairwise order (rounded squares, plain adds)
    const float zsq = np_pairwise_sum64_sq(zr);

    float bestd = 3.4e38f;
    int besti = 0;
    const int c0 = seg * CODES_PER_SEG;
    for (int cc = 0; cc < CODES_PER_SEG; cc += 4) {
        float dot[4];
#pragma unroll
        for (int u = 0; u < 4; ++u) {
            const int c = c0 + cc + u;                // uniform
            const float* wp = cb + (c << 6);
            float acc = 0.0f;
#pragma unroll
            for (int k = 0; k < D_DIM; ++k)
                acc = fmaf(zr[k], wp[k], acc);        // serial chain, k asc
            dot[u] = acc;
        }
#pragma unroll
        for (int u = 0; u < 4; ++u) {
            const int c = c0 + cc + u;
            // d = (zsq - 2*dot) + wsq, each op individually rounded
            float d = __fadd_rn(__fsub_rn(zsq, __fmul_rn(2.0f, dot[u])),
                                wsq[c]);
            if (d < bestd) { bestd = d; besti = c; }  // strict < => first min
        }
    }
    pairs[seg * NROWS + row] = make_float2(bestd, (float)besti);
}

__global__ void vq_argmin_kernel(const float2* __restrict__ pairs,
                                 float* __restrict__ codes) {
    int row = blockIdx.x * blockDim.x + threadIdx.x;
    float2 best = pairs[row];
#pragma unroll
    for (int s = 1; s < SEGS; ++s) {
        float2 p = pairs[s * NROWS + row];
        if (p.x < best.x) best = p;  // ascending seg order, strict <
    }
    codes[row] = best.y;
}

__global__ void vq_epilogue_kernel(const float* __restrict__ z,
                                   const float* __restrict__ cb,
                                   const float* __restrict__ codes,
                                   float* __restrict__ out,
                                   double* __restrict__ acc) {
    int i = blockIdx.x * 256 + threadIdx.x;  // linear index into z [b][d][t]
    int t = i & (T_DIM - 1);
    int bd = i >> 13;
    int d = bd & (D_DIM - 1);                // uniform within a wave
    int b = bd >> 6;
    int row = (b << 13) | t;

    int code = (int)codes[row];              // coalesced read
    float w = cb[(code << 6) + d];           // gather within 256 KiB (L1/L2)
    float zv = z[i];
    float diff = w - zv;                     // z_q - z
    out[i] = zv + diff;                      // z + (z_q - z), ref op order

    float v = diff * diff;
#pragma unroll
    for (int o = 32; o > 0; o >>= 1) v += __shfl_down(v, o, 64);

    __shared__ float red[4];
    if ((threadIdx.x & 63) == 0) red[threadIdx.x >> 6] = v;
    __syncthreads();
    if (threadIdx.x == 0) {
        double s = ((double)red[0] + (double)red[1]) +
                   ((double)red[2] + (double)red[3]);
        atomicAdd(acc, s);
    }
}

__global__ void vq_loss_kernel(const double* __restrict__ acc,
                               float* __restrict__ out_loss) {
    // vq_loss = codebook_loss + 0.25*commitment_loss = 1.25 * mean(diff^2)
    out_loss[0] = (float)(1.25 * (*acc) / (double)NELEM);
}

extern "C" void kernel_launch(void* const* d_in, const int* in_sizes, int n_in,
                              void* d_out, int out_size, void* d_ws, size_t ws_size,
                              hipStream_t stream) {
    const float* z  = (const float*)d_in[0];   // 4194304
    const float* cb = (const float*)d_in[1];   // 65536

    float* out      = (float*)d_out;
    float* out_loss = out + NELEM;             // index 4194304
    float* codes    = out + NELEM + 1;         // 65536 floats

    char* ws    = (char*)d_ws;
    float* wsq  = (float*)ws;
    double* acc = (double*)(ws + 4096);
    float2* pairs = (float2*)(ws + 8192);      // 2 MiB

    hipMemsetAsync(acc, 0, sizeof(double), stream);

    vq_wsq_kernel<<<C_DIM / 256, 256, 0, stream>>>(cb, wsq);

    dim3 grid1(NROWS / 256, SEGS);
    vq_dist_kernel<<<grid1, 256, 0, stream>>>(z, cb, wsq, pairs);

    vq_argmin_kernel<<<NROWS / 256, 256, 0, stream>>>(pairs, codes);

    vq_epilogue_kernel<<<NELEM / 256, 256, 0, stream>>>(z, cb, codes, out, acc);

    vq_loss_kernel<<<1, 1, 0, stream>>>(acc, out_loss);
}

// Round 3
// 303.222 us; speedup vs baseline: 1.5915x; 1.5915x over previous
//
#include <hip/hip_runtime.h>

// VectorQuantizer: z (8,64,8192) f32, codebook (1024,64) f32
// Outputs (concatenated f32): z_q_st [4194304], vq_loss [1], codes [65536]
//
// codes must match the numpy fp32 argmin BIT-EXACTLY -> replicate numpy op
// order (see vq_dist_kernel). Round-2 lesson: compiler sank the z loads into
// the code loop (VGPR=40, FETCH 10.3 GB) -> pin zr[] in VGPRs via empty asm.

#define T_DIM 8192
#define D_DIM 64
#define C_DIM 1024
#define B_DIM 8
#define NROWS (B_DIM * T_DIM)           // 65536 vectors
#define NELEM (B_DIM * D_DIM * T_DIM)   // 4194304 elements
#define SEGS 4
#define CODES_PER_SEG (C_DIM / SEGS)    // 256
#define EPI_BLOCKS (NELEM / 4 / 256)    // 4096 blocks, 1 float4/thread

// numpy pairwise_sum for exactly 64 pre-rounded squares, unfused adds.
__device__ __forceinline__ float np_pairwise_sum64_sq(const float* x) {
    float r[8];
#pragma unroll
    for (int k = 0; k < 8; ++k) r[k] = __fmul_rn(x[k], x[k]);
#pragma unroll
    for (int i = 8; i < 64; i += 8) {
#pragma unroll
        for (int k = 0; k < 8; ++k)
            r[k] = __fadd_rn(r[k], __fmul_rn(x[i + k], x[i + k]));
    }
    return __fadd_rn(
        __fadd_rn(__fadd_rn(r[0], r[1]), __fadd_rn(r[2], r[3])),
        __fadd_rn(__fadd_rn(r[4], r[5]), __fadd_rn(r[6], r[7])));
}

__global__ void vq_wsq_kernel(const float* __restrict__ cb,
                              float* __restrict__ wsq) {
    int c = blockIdx.x * blockDim.x + threadIdx.x;
    if (c >= C_DIM) return;
    float w[64];
    const float4* wp = (const float4*)(cb + (c << 6));
#pragma unroll
    for (int j = 0; j < 16; ++j) {
        float4 v = wp[j];
        w[4 * j + 0] = v.x; w[4 * j + 1] = v.y;
        w[4 * j + 2] = v.z; w[4 * j + 3] = v.w;
    }
    wsq[c] = np_pairwise_sum64_sq(w);
}

// One thread per row; blockIdx.y = 256-code segment (wave-uniform -> codebook
// reads are scalar loads). Serial FMA chain per code = BLAS sgemm accum order;
// 4 codes in flight for ILP. zr[] pinned in VGPRs (see asm) so z is fetched
// exactly once per thread.
__global__ __launch_bounds__(256, 4)
void vq_dist_kernel(const float* __restrict__ z,
                    const float* __restrict__ cb,
                    const float* __restrict__ wsq,
                    float2* __restrict__ pairs) {
    const int row = blockIdx.x * 256 + threadIdx.x;   // 0..65535
    const int seg = blockIdx.y;                       // 0..3 (uniform)
    const int b = row >> 13;                          // row / 8192
    const int t = row & (T_DIM - 1);

    // z[b, d, t]: stride T_DIM along d; lanes t-consecutive -> coalesced
    const float* zp = z + (size_t)b * (D_DIM * T_DIM) + t;
    float zr[D_DIM];
#pragma unroll
    for (int d = 0; d < D_DIM; ++d) zr[d] = zp[(size_t)d * T_DIM];
    // Pin every zr value in a VGPR: asm redefines it, so the compiler cannot
    // rematerialize the global load inside the code loop (round-2 failure
    // mode: VGPR=40, 10.3 GB HBM re-fetch).
#pragma unroll
    for (int d = 0; d < D_DIM; ++d) asm volatile("" : "+v"(zr[d]));

    // ||z||^2 with numpy's exact pairwise order (rounded squares, plain adds)
    const float zsq = np_pairwise_sum64_sq(zr);

    float bestd = 3.4e38f;
    int besti = 0;
    const int c0 = seg * CODES_PER_SEG;
    for (int cc = 0; cc < CODES_PER_SEG; cc += 4) {
        float dot[4];
#pragma unroll
        for (int u = 0; u < 4; ++u) {
            const int c = c0 + cc + u;                // uniform
            const float* wp = cb + (c << 6);
            float acc = 0.0f;
#pragma unroll
            for (int k = 0; k < D_DIM; ++k)
                acc = fmaf(zr[k], wp[k], acc);        // serial chain, k asc
            dot[u] = acc;
        }
#pragma unroll
        for (int u = 0; u < 4; ++u) {
            const int c = c0 + cc + u;
            // d = (zsq - 2*dot) + wsq, each op individually rounded
            float d = __fadd_rn(__fsub_rn(zsq, __fmul_rn(2.0f, dot[u])),
                                wsq[c]);
            if (d < bestd) { bestd = d; besti = c; }  // strict < => first min
        }
    }
    pairs[seg * NROWS + row] = make_float2(bestd, (float)besti);
}

__global__ void vq_argmin_kernel(const float2* __restrict__ pairs,
                                 float* __restrict__ codes) {
    int row = blockIdx.x * blockDim.x + threadIdx.x;
    float2 best = pairs[row];
#pragma unroll
    for (int s = 1; s < SEGS; ++s) {
        float2 p = pairs[s * NROWS + row];
        if (p.x < best.x) best = p;  // ascending seg order, strict <
    }
    codes[row] = best.y;
}

// One float4 (4 consecutive t) per thread; per-block double partial to ws
// (no global atomics -> deterministic, no serialization).
__global__ void vq_epilogue_kernel(const float* __restrict__ z,
                                   const float* __restrict__ cb,
                                   const float* __restrict__ codes,
                                   float* __restrict__ out,
                                   double* __restrict__ partials) {
    const int q = blockIdx.x * 256 + threadIdx.x;  // quad index, 0..1048575
    const int i = q << 2;                          // element index
    const int t = i & (T_DIM - 1);                 // multiple of 4
    const int bd = i >> 13;
    const int d = bd & (D_DIM - 1);                // uniform within a wave
    const int b = bd >> 6;
    const int row = (b << 13) | t;

    float4 cr = *(const float4*)(codes + row);     // 4 consecutive codes
    float4 zv = *(const float4*)(z + i);
    float w0 = cb[((int)cr.x << 6) + d];           // gathers, 256 KiB table
    float w1 = cb[((int)cr.y << 6) + d];
    float w2 = cb[((int)cr.z << 6) + d];
    float w3 = cb[((int)cr.w << 6) + d];

    float4 df = make_float4(w0 - zv.x, w1 - zv.y, w2 - zv.z, w3 - zv.w);
    float4 o = make_float4(zv.x + df.x, zv.y + df.y, zv.z + df.z, zv.w + df.w);
    *(float4*)(out + i) = o;                       // z + (z_q - z), ref order

    double v = (double)df.x * df.x + (double)df.y * df.y +
               (double)df.z * df.z + (double)df.w * df.w;
#pragma unroll
    for (int o2 = 32; o2 > 0; o2 >>= 1) v += __shfl_down(v, o2, 64);

    __shared__ double red[4];
    if ((threadIdx.x & 63) == 0) red[threadIdx.x >> 6] = v;
    __syncthreads();
    if (threadIdx.x == 0)
        partials[blockIdx.x] = ((red[0] + red[1]) + (red[2] + red[3]));
}

__global__ void vq_loss_kernel(const double* __restrict__ partials,
                               float* __restrict__ out_loss) {
    double s = 0.0;
    for (int i = threadIdx.x; i < EPI_BLOCKS; i += 256) s += partials[i];
#pragma unroll
    for (int o = 32; o > 0; o >>= 1) s += __shfl_down(s, o, 64);
    __shared__ double red[4];
    if ((threadIdx.x & 63) == 0) red[threadIdx.x >> 6] = s;
    __syncthreads();
    if (threadIdx.x == 0) {
        double tot = (red[0] + red[1]) + (red[2] + red[3]);
        // vq_loss = codebook_loss + 0.25*commitment_loss = 1.25*mean(diff^2)
        out_loss[0] = (float)(1.25 * tot / (double)NELEM);
    }
}

extern "C" void kernel_launch(void* const* d_in, const int* in_sizes, int n_in,
                              void* d_out, int out_size, void* d_ws, size_t ws_size,
                              hipStream_t stream) {
    const float* z  = (const float*)d_in[0];   // 4194304
    const float* cb = (const float*)d_in[1];   // 65536

    float* out      = (float*)d_out;
    float* out_loss = out + NELEM;             // index 4194304
    float* codes    = out + NELEM + 1;         // 65536 floats

    char* ws    = (char*)d_ws;
    float* wsq  = (float*)ws;                          // 4 KiB
    double* partials = (double*)(ws + 4096);           // 32 KiB (4096 doubles)
    float2* pairs = (float2*)(ws + 4096 + 32768);      // 2 MiB

    vq_wsq_kernel<<<C_DIM / 256, 256, 0, stream>>>(cb, wsq);

    dim3 grid1(NROWS / 256, SEGS);
    vq_dist_kernel<<<grid1, 256, 0, stream>>>(z, cb, wsq, pairs);

    vq_argmin_kernel<<<NROWS / 256, 256, 0, stream>>>(pairs, codes);

    vq_epilogue_kernel<<<EPI_BLOCKS, 256, 0, stream>>>(z, cb, codes, out, partials);

    vq_loss_kernel<<<1, 256, 0, stream>>>(partials, out_loss);
}

// Round 4
// 271.525 us; speedup vs baseline: 1.7773x; 1.1167x over previous
//
#include <hip/hip_runtime.h>

// VectorQuantizer: z (8,64,8192) f32, codebook (1024,64) f32
// Outputs (concatenated f32): z_q_st [4194304], vq_loss [1], codes [65536]
//
// codes must match numpy fp32 argmin BIT-EXACTLY -> replicate numpy op order:
//   zsq/wsq: pairwise_sum n=64 (8 serial column accumulators, rounded squares)
//   dot:     single serial FMA chain over k ascending (BLAS sgemm order)
//   dist:    fl(fl(zsq - fl(2*dot)) + wsq), argmin = first occurrence of min.
//
// Round-3 lesson: float zr[64] passed by pointer to a helper -> SROA failed,
// array demoted to scratch (VGPR=40, 10.3 GB HBM from scratch thrash).
// Fix: 64 NAMED scalars via macros. No array, no address, no scratch.

#define T_DIM 8192
#define D_DIM 64
#define C_DIM 1024
#define B_DIM 8
#define NROWS (B_DIM * T_DIM)           // 65536 vectors
#define NELEM (B_DIM * D_DIM * T_DIM)   // 4194304 elements
#define SEGS 4
#define CODES_PER_SEG (C_DIM / SEGS)    // 256
#define EPI_BLOCKS (NELEM / 4 / 256)    // 4096 blocks, 1 float4/thread

#define R64(M) M(0) M(1) M(2) M(3) M(4) M(5) M(6) M(7) \
  M(8) M(9) M(10) M(11) M(12) M(13) M(14) M(15) \
  M(16) M(17) M(18) M(19) M(20) M(21) M(22) M(23) \
  M(24) M(25) M(26) M(27) M(28) M(29) M(30) M(31) \
  M(32) M(33) M(34) M(35) M(36) M(37) M(38) M(39) \
  M(40) M(41) M(42) M(43) M(44) M(45) M(46) M(47) \
  M(48) M(49) M(50) M(51) M(52) M(53) M(54) M(55) \
  M(56) M(57) M(58) M(59) M(60) M(61) M(62) M(63)

#define SQ_(x) __fmul_rn(x, x)
#define AD_(a, b) __fadd_rn(a, b)

// numpy pairwise_sum of 64 pre-rounded squares of scalars p0..p63 -> dst.
// Column j accumulates p{j}, p{j+8}, ..., p{j+56} serially; columns combined
// ((r0+r1)+(r2+r3)) + ((r4+r5)+(r6+r7)). All ops individually rounded.
#define PAIRWISE64(p, dst) \
  float pr0 = SQ_(p##0);  pr0 = AD_(pr0, SQ_(p##8));  pr0 = AD_(pr0, SQ_(p##16)); pr0 = AD_(pr0, SQ_(p##24)); pr0 = AD_(pr0, SQ_(p##32)); pr0 = AD_(pr0, SQ_(p##40)); pr0 = AD_(pr0, SQ_(p##48)); pr0 = AD_(pr0, SQ_(p##56)); \
  float pr1 = SQ_(p##1);  pr1 = AD_(pr1, SQ_(p##9));  pr1 = AD_(pr1, SQ_(p##17)); pr1 = AD_(pr1, SQ_(p##25)); pr1 = AD_(pr1, SQ_(p##33)); pr1 = AD_(pr1, SQ_(p##41)); pr1 = AD_(pr1, SQ_(p##49)); pr1 = AD_(pr1, SQ_(p##57)); \
  float pr2 = SQ_(p##2);  pr2 = AD_(pr2, SQ_(p##10)); pr2 = AD_(pr2, SQ_(p##18)); pr2 = AD_(pr2, SQ_(p##26)); pr2 = AD_(pr2, SQ_(p##34)); pr2 = AD_(pr2, SQ_(p##42)); pr2 = AD_(pr2, SQ_(p##50)); pr2 = AD_(pr2, SQ_(p##58)); \
  float pr3 = SQ_(p##3);  pr3 = AD_(pr3, SQ_(p##11)); pr3 = AD_(pr3, SQ_(p##19)); pr3 = AD_(pr3, SQ_(p##27)); pr3 = AD_(pr3, SQ_(p##35)); pr3 = AD_(pr3, SQ_(p##43)); pr3 = AD_(pr3, SQ_(p##51)); pr3 = AD_(pr3, SQ_(p##59)); \
  float pr4 = SQ_(p##4);  pr4 = AD_(pr4, SQ_(p##12)); pr4 = AD_(pr4, SQ_(p##20)); pr4 = AD_(pr4, SQ_(p##28)); pr4 = AD_(pr4, SQ_(p##36)); pr4 = AD_(pr4, SQ_(p##44)); pr4 = AD_(pr4, SQ_(p##52)); pr4 = AD_(pr4, SQ_(p##60)); \
  float pr5 = SQ_(p##5);  pr5 = AD_(pr5, SQ_(p##13)); pr5 = AD_(pr5, SQ_(p##21)); pr5 = AD_(pr5, SQ_(p##29)); pr5 = AD_(pr5, SQ_(p##37)); pr5 = AD_(pr5, SQ_(p##45)); pr5 = AD_(pr5, SQ_(p##53)); pr5 = AD_(pr5, SQ_(p##61)); \
  float pr6 = SQ_(p##6);  pr6 = AD_(pr6, SQ_(p##14)); pr6 = AD_(pr6, SQ_(p##22)); pr6 = AD_(pr6, SQ_(p##30)); pr6 = AD_(pr6, SQ_(p##38)); pr6 = AD_(pr6, SQ_(p##46)); pr6 = AD_(pr6, SQ_(p##54)); pr6 = AD_(pr6, SQ_(p##62)); \
  float pr7 = SQ_(p##7);  pr7 = AD_(pr7, SQ_(p##15)); pr7 = AD_(pr7, SQ_(p##23)); pr7 = AD_(pr7, SQ_(p##31)); pr7 = AD_(pr7, SQ_(p##39)); pr7 = AD_(pr7, SQ_(p##47)); pr7 = AD_(pr7, SQ_(p##55)); pr7 = AD_(pr7, SQ_(p##63)); \
  float dst = AD_(AD_(AD_(pr0, pr1), AD_(pr2, pr3)), AD_(AD_(pr4, pr5), AD_(pr6, pr7)));

__global__ void vq_wsq_kernel(const float* __restrict__ cb,
                              float* __restrict__ wsq) {
    int c = blockIdx.x * blockDim.x + threadIdx.x;
    if (c >= C_DIM) return;
    const float* wp = cb + (c << 6);
#define LOADW(k) float w##k = wp[k];
    R64(LOADW)
#undef LOADW
    PAIRWISE64(w, s)
    wsq[c] = s;
}

// One thread per row; blockIdx.y = 256-code segment (wave-uniform -> codebook
// reads are scalar s_loads). 64 named scalar z regs; serial FMA chain per
// code (sgemm accumulation order); 4 interleaved chains for ILP.
__global__ __launch_bounds__(256, 4)
void vq_dist_kernel(const float* __restrict__ z,
                    const float* __restrict__ cb,
                    const float* __restrict__ wsq,
                    float2* __restrict__ pairs) {
    const int row = blockIdx.x * 256 + threadIdx.x;   // 0..65535
    const int seg = blockIdx.y;                       // 0..3 (uniform)
    const int b = row >> 13;                          // row / 8192
    const int t = row & (T_DIM - 1);

    // z[b, d, t]: stride T_DIM along d; lanes t-consecutive -> coalesced
    const float* zp = z + (size_t)b * (D_DIM * T_DIM) + t;
#define LOADZ(k) float z##k = zp[(size_t)k * T_DIM];
    R64(LOADZ)
#undef LOADZ

    // ||z||^2 in numpy's exact pairwise order
    PAIRWISE64(z, zsq)

    float bestd = 3.4e38f;
    int besti = 0;
    const int c0 = seg * CODES_PER_SEG;
#pragma unroll 1
    for (int cc = 0; cc < CODES_PER_SEG; cc += 4) {
        const float* wpa = cb + ((size_t)(c0 + cc) << 6);  // uniform
        const float* wpb = wpa + 64;
        const float* wpc = wpa + 128;
        const float* wpd = wpa + 192;
        float a0 = 0.f, a1 = 0.f, a2 = 0.f, a3 = 0.f;
#define DOT4(k) a0 = fmaf(z##k, wpa[k], a0); \
                a1 = fmaf(z##k, wpb[k], a1); \
                a2 = fmaf(z##k, wpc[k], a2); \
                a3 = fmaf(z##k, wpd[k], a3);
        R64(DOT4)
#undef DOT4
        // d = (zsq - 2*dot) + wsq, each op individually rounded; codes
        // checked in ascending order with strict < => first-min semantics.
        float d0 = __fadd_rn(__fsub_rn(zsq, __fmul_rn(2.0f, a0)), wsq[c0 + cc + 0]);
        float d1 = __fadd_rn(__fsub_rn(zsq, __fmul_rn(2.0f, a1)), wsq[c0 + cc + 1]);
        float d2 = __fadd_rn(__fsub_rn(zsq, __fmul_rn(2.0f, a2)), wsq[c0 + cc + 2]);
        float d3 = __fadd_rn(__fsub_rn(zsq, __fmul_rn(2.0f, a3)), wsq[c0 + cc + 3]);
        if (d0 < bestd) { bestd = d0; besti = c0 + cc + 0; }
        if (d1 < bestd) { bestd = d1; besti = c0 + cc + 1; }
        if (d2 < bestd) { bestd = d2; besti = c0 + cc + 2; }
        if (d3 < bestd) { bestd = d3; besti = c0 + cc + 3; }
    }
    pairs[seg * NROWS + row] = make_float2(bestd, (float)besti);
}

__global__ void vq_argmin_kernel(const float2* __restrict__ pairs,
                                 float* __restrict__ codes) {
    int row = blockIdx.x * blockDim.x + threadIdx.x;
    float2 best = pairs[row];
#pragma unroll
    for (int s = 1; s < SEGS; ++s) {
        float2 p = pairs[s * NROWS + row];
        if (p.x < best.x) best = p;  // ascending seg order, strict <
    }
    codes[row] = best.y;
}

// One float4 (4 consecutive t) per thread; per-block double partial to ws
// (no global atomics -> deterministic, no serialization).
__global__ void vq_epilogue_kernel(const float* __restrict__ z,
                                   const float* __restrict__ cb,
                                   const float* __restrict__ codes,
                                   float* __restrict__ out,
                                   double* __restrict__ partials) {
    const int q = blockIdx.x * 256 + threadIdx.x;  // quad index, 0..1048575
    const int i = q << 2;                          // element index
    const int t = i & (T_DIM - 1);                 // multiple of 4
    const int bd = i >> 13;
    const int d = bd & (D_DIM - 1);                // uniform within a wave
    const int b = bd >> 6;
    const int row = (b << 13) | t;

    float4 cr = *(const float4*)(codes + row);     // 4 consecutive codes
    float4 zv = *(const float4*)(z + i);
    float w0 = cb[((int)cr.x << 6) + d];           // gathers, 256 KiB table
    float w1 = cb[((int)cr.y << 6) + d];
    float w2 = cb[((int)cr.z << 6) + d];
    float w3 = cb[((int)cr.w << 6) + d];

    float4 df = make_float4(w0 - zv.x, w1 - zv.y, w2 - zv.z, w3 - zv.w);
    float4 o = make_float4(zv.x + df.x, zv.y + df.y, zv.z + df.z, zv.w + df.w);
    *(float4*)(out + i) = o;                       // z + (z_q - z), ref order

    double v = (double)df.x * df.x + (double)df.y * df.y +
               (double)df.z * df.z + (double)df.w * df.w;
#pragma unroll
    for (int o2 = 32; o2 > 0; o2 >>= 1) v += __shfl_down(v, o2, 64);

    __shared__ double red[4];
    if ((threadIdx.x & 63) == 0) red[threadIdx.x >> 6] = v;
    __syncthreads();
    if (threadIdx.x == 0)
        partials[blockIdx.x] = ((red[0] + red[1]) + (red[2] + red[3]));
}

__global__ void vq_loss_kernel(const double* __restrict__ partials,
                               float* __restrict__ out_loss) {
    double s = 0.0;
    for (int i = threadIdx.x; i < EPI_BLOCKS; i += 256) s += partials[i];
#pragma unroll
    for (int o = 32; o > 0; o >>= 1) s += __shfl_down(s, o, 64);
    __shared__ double red[4];
    if ((threadIdx.x & 63) == 0) red[threadIdx.x >> 6] = s;
    __syncthreads();
    if (threadIdx.x == 0) {
        double tot = (red[0] + red[1]) + (red[2] + red[3]);
        // vq_loss = codebook_loss + 0.25*commitment_loss = 1.25*mean(diff^2)
        out_loss[0] = (float)(1.25 * tot / (double)NELEM);
    }
}

extern "C" void kernel_launch(void* const* d_in, const int* in_sizes, int n_in,
                              void* d_out, int out_size, void* d_ws, size_t ws_size,
                              hipStream_t stream) {
    const float* z  = (const float*)d_in[0];   // 4194304
    const float* cb = (const float*)d_in[1];   // 65536

    float* out      = (float*)d_out;
    float* out_loss = out + NELEM;             // index 4194304
    float* codes    = out + NELEM + 1;         // 65536 floats

    char* ws    = (char*)d_ws;
    float* wsq  = (float*)ws;                          // 4 KiB
    double* partials = (double*)(ws + 4096);           // 32 KiB (4096 doubles)
    float2* pairs = (float2*)(ws + 4096 + 32768);      // 2 MiB

    vq_wsq_kernel<<<C_DIM / 256, 256, 0, stream>>>(cb, wsq);

    dim3 grid1(NROWS / 256, SEGS);
    vq_dist_kernel<<<grid1, 256, 0, stream>>>(z, cb, wsq, pairs);

    vq_argmin_kernel<<<NROWS / 256, 256, 0, stream>>>(pairs, codes);

    vq_epilogue_kernel<<<EPI_BLOCKS, 256, 0, stream>>>(z, cb, codes, out, partials);

    vq_loss_kernel<<<1, 256, 0, stream>>>(partials, out_loss);
}

// Round 5
// 262.591 us; speedup vs baseline: 1.8377x; 1.0340x over previous
//
#include <hip/hip_runtime.h>

// VectorQuantizer: z (8,64,8192) f32, codebook (1024,64) f32
// Outputs (concatenated f32): z_q_st [4194304], vq_loss [1], codes [65536]
//
// codes must match numpy fp32 argmin BIT-EXACTLY -> replicate numpy op order:
//   zsq/wsq: pairwise_sum n=64 (8 serial column accumulators, rounded squares)
//   dot:     single serial FMA chain over k ascending (BLAS sgemm order)
//   dist:    fl(fl(zsq - fl(2*dot)) + wsq), argmin = first occurrence of min.
//
// R3 lesson: float zr[64] by pointer -> scratch demotion (VGPR=40, 10 GB HBM).
// R4 lesson: named scalars alone -> compiler SINKS the (rematerializable)
//   z-loads back into the code loop: same VGPR=40, same 10.3 GB re-fetch.
// R5 fix: named scalars + per-value `asm volatile("" : "+v")` pin. The asm
//   def is not rematerializable/duplicable, so the 64 values MUST stay in
//   VGPRs across the loop (~90 regs, fits the 128-reg cap of (256,4)).

#define T_DIM 8192
#define D_DIM 64
#define C_DIM 1024
#define B_DIM 8
#define NROWS (B_DIM * T_DIM)           // 65536 vectors
#define NELEM (B_DIM * D_DIM * T_DIM)   // 4194304 elements
#define SEGS 4
#define CODES_PER_SEG (C_DIM / SEGS)    // 256
#define EPI_BLOCKS (NELEM / 4 / 256)    // 4096 blocks, 1 float4/thread

#define R64(M) M(0) M(1) M(2) M(3) M(4) M(5) M(6) M(7) \
  M(8) M(9) M(10) M(11) M(12) M(13) M(14) M(15) \
  M(16) M(17) M(18) M(19) M(20) M(21) M(22) M(23) \
  M(24) M(25) M(26) M(27) M(28) M(29) M(30) M(31) \
  M(32) M(33) M(34) M(35) M(36) M(37) M(38) M(39) \
  M(40) M(41) M(42) M(43) M(44) M(45) M(46) M(47) \
  M(48) M(49) M(50) M(51) M(52) M(53) M(54) M(55) \
  M(56) M(57) M(58) M(59) M(60) M(61) M(62) M(63)

#define SQ_(x) __fmul_rn(x, x)
#define AD_(a, b) __fadd_rn(a, b)

// numpy pairwise_sum of 64 pre-rounded squares of scalars p0..p63 -> dst.
// Column j accumulates p{j}, p{j+8}, ..., p{j+56} serially; columns combined
// ((r0+r1)+(r2+r3)) + ((r4+r5)+(r6+r7)). All ops individually rounded.
#define PAIRWISE64(p, dst) \
  float pr0 = SQ_(p##0);  pr0 = AD_(pr0, SQ_(p##8));  pr0 = AD_(pr0, SQ_(p##16)); pr0 = AD_(pr0, SQ_(p##24)); pr0 = AD_(pr0, SQ_(p##32)); pr0 = AD_(pr0, SQ_(p##40)); pr0 = AD_(pr0, SQ_(p##48)); pr0 = AD_(pr0, SQ_(p##56)); \
  float pr1 = SQ_(p##1);  pr1 = AD_(pr1, SQ_(p##9));  pr1 = AD_(pr1, SQ_(p##17)); pr1 = AD_(pr1, SQ_(p##25)); pr1 = AD_(pr1, SQ_(p##33)); pr1 = AD_(pr1, SQ_(p##41)); pr1 = AD_(pr1, SQ_(p##49)); pr1 = AD_(pr1, SQ_(p##57)); \
  float pr2 = SQ_(p##2);  pr2 = AD_(pr2, SQ_(p##10)); pr2 = AD_(pr2, SQ_(p##18)); pr2 = AD_(pr2, SQ_(p##26)); pr2 = AD_(pr2, SQ_(p##34)); pr2 = AD_(pr2, SQ_(p##42)); pr2 = AD_(pr2, SQ_(p##50)); pr2 = AD_(pr2, SQ_(p##58)); \
  float pr3 = SQ_(p##3);  pr3 = AD_(pr3, SQ_(p##11)); pr3 = AD_(pr3, SQ_(p##19)); pr3 = AD_(pr3, SQ_(p##27)); pr3 = AD_(pr3, SQ_(p##35)); pr3 = AD_(pr3, SQ_(p##43)); pr3 = AD_(pr3, SQ_(p##51)); pr3 = AD_(pr3, SQ_(p##59)); \
  float pr4 = SQ_(p##4);  pr4 = AD_(pr4, SQ_(p##12)); pr4 = AD_(pr4, SQ_(p##20)); pr4 = AD_(pr4, SQ_(p##28)); pr4 = AD_(pr4, SQ_(p##36)); pr4 = AD_(pr4, SQ_(p##44)); pr4 = AD_(pr4, SQ_(p##52)); pr4 = AD_(pr4, SQ_(p##60)); \
  float pr5 = SQ_(p##5);  pr5 = AD_(pr5, SQ_(p##13)); pr5 = AD_(pr5, SQ_(p##21)); pr5 = AD_(pr5, SQ_(p##29)); pr5 = AD_(pr5, SQ_(p##37)); pr5 = AD_(pr5, SQ_(p##45)); pr5 = AD_(pr5, SQ_(p##53)); pr5 = AD_(pr5, SQ_(p##61)); \
  float pr6 = SQ_(p##6);  pr6 = AD_(pr6, SQ_(p##14)); pr6 = AD_(pr6, SQ_(p##22)); pr6 = AD_(pr6, SQ_(p##30)); pr6 = AD_(pr6, SQ_(p##38)); pr6 = AD_(pr6, SQ_(p##46)); pr6 = AD_(pr6, SQ_(p##54)); pr6 = AD_(pr6, SQ_(p##62)); \
  float pr7 = SQ_(p##7);  pr7 = AD_(pr7, SQ_(p##15)); pr7 = AD_(pr7, SQ_(p##23)); pr7 = AD_(pr7, SQ_(p##31)); pr7 = AD_(pr7, SQ_(p##39)); pr7 = AD_(pr7, SQ_(p##47)); pr7 = AD_(pr7, SQ_(p##55)); pr7 = AD_(pr7, SQ_(p##63)); \
  float dst = AD_(AD_(AD_(pr0, pr1), AD_(pr2, pr3)), AD_(AD_(pr4, pr5), AD_(pr6, pr7)));

// One thread per row; blockIdx.y = 256-code segment (wave-uniform -> codebook
// reads are scalar s_loads). Per-block wsq for the segment computed into LDS
// (replaces the separate wsq kernel). 64 pinned z regs; serial FMA chain per
// code (sgemm accumulation order); 4 interleaved chains for ILP.
__global__ __launch_bounds__(256, 4)
void vq_dist_kernel(const float* __restrict__ z,
                    const float* __restrict__ cb,
                    float2* __restrict__ pairs) {
    const int row = blockIdx.x * 256 + threadIdx.x;   // 0..65535
    const int seg = blockIdx.y;                       // 0..3 (uniform)
    const int c0 = seg * CODES_PER_SEG;
    const int b = row >> 13;                          // row / 8192
    const int t = row & (T_DIM - 1);

    // --- per-block ||w||^2 for this segment's 256 codes (numpy op order) ---
    __shared__ float wsqs[CODES_PER_SEG];
    {
        const float* wp = cb + ((size_t)(c0 + threadIdx.x) << 6);
#define LOADW(k) float w##k = wp[k];
        R64(LOADW)
#undef LOADW
        PAIRWISE64(w, s)
        wsqs[threadIdx.x] = s;
    }
    __syncthreads();

    // --- z row into 64 pinned VGPRs ---
    // z[b, d, t]: stride T_DIM along d; lanes t-consecutive -> coalesced
    const float* zp = z + (size_t)b * (D_DIM * T_DIM) + t;
#define LOADZ(k) float z##k = zp[(size_t)k * T_DIM]; \
                 asm volatile("" : "+v"(z##k));
    R64(LOADZ)
#undef LOADZ

    // ||z||^2 in numpy's exact pairwise order
    PAIRWISE64(z, zsq)

    float bestd = 3.4e38f;
    int besti = 0;
#pragma unroll 1
    for (int cc = 0; cc < CODES_PER_SEG; cc += 4) {
        const float* wpa = cb + ((size_t)(c0 + cc) << 6);  // uniform
        const float* wpb = wpa + 64;
        const float* wpc = wpa + 128;
        const float* wpd = wpa + 192;
        float a0 = 0.f, a1 = 0.f, a2 = 0.f, a3 = 0.f;
#define DOT4(k) a0 = fmaf(z##k, wpa[k], a0); \
                a1 = fmaf(z##k, wpb[k], a1); \
                a2 = fmaf(z##k, wpc[k], a2); \
                a3 = fmaf(z##k, wpd[k], a3);
        R64(DOT4)
#undef DOT4
        // d = (zsq - 2*dot) + wsq, each op individually rounded; codes
        // checked in ascending order with strict < => first-min semantics.
        float d0 = __fadd_rn(__fsub_rn(zsq, __fmul_rn(2.0f, a0)), wsqs[cc + 0]);
        float d1 = __fadd_rn(__fsub_rn(zsq, __fmul_rn(2.0f, a1)), wsqs[cc + 1]);
        float d2 = __fadd_rn(__fsub_rn(zsq, __fmul_rn(2.0f, a2)), wsqs[cc + 2]);
        float d3 = __fadd_rn(__fsub_rn(zsq, __fmul_rn(2.0f, a3)), wsqs[cc + 3]);
        if (d0 < bestd) { bestd = d0; besti = c0 + cc + 0; }
        if (d1 < bestd) { bestd = d1; besti = c0 + cc + 1; }
        if (d2 < bestd) { bestd = d2; besti = c0 + cc + 2; }
        if (d3 < bestd) { bestd = d3; besti = c0 + cc + 3; }
    }
    pairs[seg * NROWS + row] = make_float2(bestd, (float)besti);
}

__global__ void vq_argmin_kernel(const float2* __restrict__ pairs,
                                 float* __restrict__ codes) {
    int row = blockIdx.x * blockDim.x + threadIdx.x;
    float2 best = pairs[row];
#pragma unroll
    for (int s = 1; s < SEGS; ++s) {
        float2 p = pairs[s * NROWS + row];
        if (p.x < best.x) best = p;  // ascending seg order, strict <
    }
    codes[row] = best.y;
}

// One float4 (4 consecutive t) per thread; per-block double partial to ws
// (no global atomics -> deterministic, no serialization).
__global__ void vq_epilogue_kernel(const float* __restrict__ z,
                                   const float* __restrict__ cb,
                                   const float* __restrict__ codes,
                                   float* __restrict__ out,
                                   double* __restrict__ partials) {
    const int q = blockIdx.x * 256 + threadIdx.x;  // quad index, 0..1048575
    const int i = q << 2;                          // element index
    const int t = i & (T_DIM - 1);                 // multiple of 4
    const int bd = i >> 13;
    const int d = bd & (D_DIM - 1);                // uniform within a wave
    const int b = bd >> 6;
    const int row = (b << 13) | t;

    float4 cr = *(const float4*)(codes + row);     // 4 consecutive codes
    float4 zv = *(const float4*)(z + i);
    float w0 = cb[((int)cr.x << 6) + d];           // gathers, 256 KiB table
    float w1 = cb[((int)cr.y << 6) + d];
    float w2 = cb[((int)cr.z << 6) + d];
    float w3 = cb[((int)cr.w << 6) + d];

    float4 df = make_float4(w0 - zv.x, w1 - zv.y, w2 - zv.z, w3 - zv.w);
    float4 o = make_float4(zv.x + df.x, zv.y + df.y, zv.z + df.z, zv.w + df.w);
    *(float4*)(out + i) = o;                       // z + (z_q - z), ref order

    double v = (double)df.x * df.x + (double)df.y * df.y +
               (double)df.z * df.z + (double)df.w * df.w;
#pragma unroll
    for (int o2 = 32; o2 > 0; o2 >>= 1) v += __shfl_down(v, o2, 64);

    __shared__ double red[4];
    if ((threadIdx.x & 63) == 0) red[threadIdx.x >> 6] = v;
    __syncthreads();
    if (threadIdx.x == 0)
        partials[blockIdx.x] = ((red[0] + red[1]) + (red[2] + red[3]));
}

__global__ void vq_loss_kernel(const double* __restrict__ partials,
                               float* __restrict__ out_loss) {
    double s = 0.0;
    for (int i = threadIdx.x; i < EPI_BLOCKS; i += 256) s += partials[i];
#pragma unroll
    for (int o = 32; o > 0; o >>= 1) s += __shfl_down(s, o, 64);
    __shared__ double red[4];
    if ((threadIdx.x & 63) == 0) red[threadIdx.x >> 6] = s;
    __syncthreads();
    if (threadIdx.x == 0) {
        double tot = (red[0] + red[1]) + (red[2] + red[3]);
        // vq_loss = codebook_loss + 0.25*commitment_loss = 1.25*mean(diff^2)
        out_loss[0] = (float)(1.25 * tot / (double)NELEM);
    }
}

extern "C" void kernel_launch(void* const* d_in, const int* in_sizes, int n_in,
                              void* d_out, int out_size, void* d_ws, size_t ws_size,
                              hipStream_t stream) {
    const float* z  = (const float*)d_in[0];   // 4194304
    const float* cb = (const float*)d_in[1];   // 65536

    float* out      = (float*)d_out;
    float* out_loss = out + NELEM;             // index 4194304
    float* codes    = out + NELEM + 1;         // 65536 floats

    char* ws    = (char*)d_ws;
    double* partials = (double*)(ws);                  // 32 KiB (4096 doubles)
    float2* pairs = (float2*)(ws + 32768);             // 2 MiB

    dim3 grid1(NROWS / 256, SEGS);
    vq_dist_kernel<<<grid1, 256, 0, stream>>>(z, cb, pairs);

    vq_argmin_kernel<<<NROWS / 256, 256, 0, stream>>>(pairs, codes);

    vq_epilogue_kernel<<<EPI_BLOCKS, 256, 0, stream>>>(z, cb, codes, out, partials);

    vq_loss_kernel<<<1, 256, 0, stream>>>(partials, out_loss);
}